// Round 12
// baseline (380.817 us; speedup 1.0000x reference)
//
#include <hip/hip_runtime.h>
#include <hip/hip_bf16.h>
#include <cstddef>
#include <cstdint>

#define NROWS 8192
#define LOG2E 1.4426950408889634f

typedef __attribute__((ext_vector_type(8))) short bf16x8;
typedef __attribute__((ext_vector_type(4))) float f32x4;
typedef __attribute__((ext_vector_type(16))) float f32x16;

#define EXP2(x) __builtin_amdgcn_exp2f(x)

__device__ __forceinline__ short f2bf(float f) {
  unsigned u = __float_as_uint(f);
  u += 0x7fffu + ((u >> 16) & 1u);   // RNE
  return (short)(u >> 16);
}
__device__ __forceinline__ float leaky_f(float v) { return fmaxf(v, 0.1f * v); }

union BFPair { __hip_bfloat162 h; unsigned u; };
__device__ __forceinline__ unsigned pack2(float a, float b) {
  BFPair p;
  p.h = __float22bfloat162_rn(make_float2(a, b));  // v_cvt_pk_bf16_f32
  return p.u;
}
__device__ __forceinline__ f32x4 ntload4(const float* p) {
  return __builtin_nontemporal_load((const f32x4*)p);
}

// ---------------- Kernel 1: MLP encoder: x[8192,256] -> x2, s(prescaled), sq, x2bfT --
extern "C" __global__ void __launch_bounds__(256)
encoder_kernel(const float* __restrict__ x, const float* __restrict__ W10,
               const float* __restrict__ b10, const float* __restrict__ W11,
               const float* __restrict__ b11, const float* __restrict__ avec,
               float* __restrict__ x2, float* __restrict__ sarr,
               float* __restrict__ sqarr, short* __restrict__ x2bfT) {
  __shared__ float xr[4][256];
  __shared__ float h1[4][128];
  const int t = threadIdx.x;
  const int r0 = blockIdx.x * 4;
#pragma unroll
  for (int r = 0; r < 4; ++r) xr[r][t] = x[(size_t)(r0 + r) * 256 + t];
  __syncthreads();
  if (t < 128) {
    float acc[4];
    const float b = b10[t];
#pragma unroll
    for (int r = 0; r < 4; ++r) acc[r] = b;
    const float* wrow = W10 + t * 256;
    for (int c = 0; c < 256; c += 4) {
      const float4 wv = *(const float4*)(wrow + c);
#pragma unroll
      for (int r = 0; r < 4; ++r) {
        acc[r] = fmaf(wv.x, xr[r][c], acc[r]);
        acc[r] = fmaf(wv.y, xr[r][c + 1], acc[r]);
        acc[r] = fmaf(wv.z, xr[r][c + 2], acc[r]);
        acc[r] = fmaf(wv.w, xr[r][c + 3], acc[r]);
      }
    }
#pragma unroll
    for (int r = 0; r < 4; ++r) h1[r][t] = leaky_f(acc[r]);
  }
  __syncthreads();
  if (t < 64) {
    float acc[4];
    const float b = b11[t];
#pragma unroll
    for (int r = 0; r < 4; ++r) acc[r] = b;
    const float* wrow = W11 + t * 128;
    for (int c = 0; c < 128; c += 4) {
      const float4 wv = *(const float4*)(wrow + c);
#pragma unroll
      for (int r = 0; r < 4; ++r) {
        acc[r] = fmaf(wv.x, h1[r][c], acc[r]);
        acc[r] = fmaf(wv.y, h1[r][c + 1], acc[r]);
        acc[r] = fmaf(wv.z, h1[r][c + 2], acc[r]);
        acc[r] = fmaf(wv.w, h1[r][c + 3], acc[r]);
      }
    }
    const float av = avec[t];
#pragma unroll
    for (int r = 0; r < 4; ++r) {
      const float v = leaky_f(acc[r]);
      x2[(size_t)(r0 + r) * 64 + t] = v;
      x2bfT[(size_t)t * NROWS + r0 + r] = f2bf(v);
      float ps = v * av, pq = v * v;
#pragma unroll
      for (int off = 1; off < 64; off <<= 1) {
        ps += __shfl_xor(ps, off);
        pq += __shfl_xor(pq, off);
      }
      if (t == 0) {
        sarr[r0 + r] = ps * LOG2E;          // exp(leaky(d)) = exp2(leaky(d*log2e))
        sqarr[r0 + r] = pq * (1.0f / 64.0f);
      }
    }
  }
}

// ======================= CALIBRATION KERNELS (outputs unused) =======================

// K_a: pure-read benchmark, m13 pattern, TWO passes over A (512 MB of reads).
extern "C" __global__ void __launch_bounds__(256)
readbench_kernel(const float* __restrict__ A, float* __restrict__ osum) {
  __shared__ float red[256];
  const int t = threadIdx.x;
  const size_t stride = (size_t)gridDim.x * 256;
  const size_t nvec = (size_t)NROWS * NROWS / 4;
  float acc = 0.f;
#pragma unroll 1
  for (int p = 0; p < 2; ++p)
#pragma unroll 1
    for (size_t v = (size_t)blockIdx.x * 256 + t; v < nvec; v += stride) {
      const f32x4 a = *(const f32x4*)(A + v * 4);
      acc += (a[0] + a[1]) + (a[2] + a[3]);
    }
  red[t] = acc;
  __syncthreads();
  for (int off = 128; off > 0; off >>= 1) {
    if (t < off) red[t] += red[t + off];
    __syncthreads();
  }
  if (t == 0) osum[blockIdx.x] = red[0];
}

// K_b: read + exp2/leaky chain + scalar sums, NO stores beyond block sums.
extern "C" __global__ void __launch_bounds__(256)
expbench_kernel(const float* __restrict__ A, const float* __restrict__ sarr,
                const float* __restrict__ sqarr, float* __restrict__ osum) {
  __shared__ float red[256];
  const int t = threadIdx.x;
  const size_t stride = (size_t)gridDim.x * 256;
  const size_t nvec = (size_t)NROWS * NROWS / 4;
  float s0 = 0.f, s1 = 0.f, s2 = 0.f;
#pragma unroll 1
  for (size_t v = (size_t)blockIdx.x * 256 + t; v < nvec; v += stride) {
    const size_t e = v * 4;
    const int i = (int)(e >> 13);
    const int j = (int)(e & 8191);
    const float sif = sarr[i];
    const f32x4 a4 = *(const f32x4*)(A + e);
    const f32x4 sj = *(const f32x4*)(sarr + j);
    const f32x4 sq = *(const f32x4*)(sqarr + j);
    const float d0 = sif - sj[0], d1 = sif - sj[1];
    const float d2 = sif - sj[2], d3 = sif - sj[3];
    const float r0 = EXP2(fmaxf(d0, 0.1f * d0)) * a4[0];
    const float r1 = EXP2(fmaxf(d1, 0.1f * d1)) * a4[1];
    const float r2 = EXP2(fmaxf(d2, 0.1f * d2)) * a4[2];
    const float r3 = EXP2(fmaxf(d3, 0.1f * d3)) * a4[3];
    s0 += (r0 + r1) + (r2 + r3);
    s1 = fmaf(r0, r0, fmaf(r1, r1, fmaf(r2, r2, fmaf(r3, r3, s1))));
    s2 = fmaf(r0, sq[0], fmaf(r1, sq[1], fmaf(r2, sq[2], fmaf(r3, sq[3], s2))));
  }
  red[t] = s0 + s1 + s2;
  __syncthreads();
  for (int off = 128; off > 0; off >>= 1) {
    if (t < off) red[t] += red[t + off];
    __syncthreads();
  }
  if (t == 0) osum[blockIdx.x] = red[0];
}

// K_c: round-11 convert verbatim — read + transform + 128MB bf16 store + partials.
extern "C" __global__ void __launch_bounds__(256)
convbench_kernel(const float* __restrict__ A, const float* __restrict__ sarr,
                 const float* __restrict__ sqarr, short* __restrict__ raw,
                 float* __restrict__ rspc, float* __restrict__ sspc,
                 float* __restrict__ wspc) {
  const int t = threadIdx.x, l = t & 63, w = t >> 6;
  const int gw = blockIdx.x * 4 + w;          // 0..8191
#pragma unroll 1
  for (int k = 0; k < 32; ++k) {
    const int chunk = gw + k * 8192;
    const int i = chunk >> 5;
    const int jc = (chunk & 31) << 8;
    const float sif = sarr[i];
    const f32x4 a4 = ntload4(A + (size_t)chunk * 256 + l * 4);
    const f32x4 sj = *(const f32x4*)(sarr + jc + l * 4);
    const f32x4 sq = *(const f32x4*)(sqarr + jc + l * 4);
    const float d0 = sif - sj[0], d1 = sif - sj[1];
    const float d2 = sif - sj[2], d3 = sif - sj[3];
    const float r0 = EXP2(fmaxf(d0, 0.1f * d0)) * a4[0];
    const float r1 = EXP2(fmaxf(d1, 0.1f * d1)) * a4[1];
    const float r2 = EXP2(fmaxf(d2, 0.1f * d2)) * a4[2];
    const float r3 = EXP2(fmaxf(d3, 0.1f * d3)) * a4[3];
    uint2 pk;
    pk.x = pack2(r0, r1);
    pk.y = pack2(r2, r3);
    *(uint2*)(raw + (size_t)chunk * 256 + l * 4) = pk;
    float a = (r0 + r1) + (r2 + r3);
    float b = fmaf(r0, r0, fmaf(r1, r1, fmaf(r2, r2, r3 * r3)));
    float c = fmaf(r0, sq[0], fmaf(r1, sq[1], fmaf(r2, sq[2], r3 * sq[3])));
#pragma unroll
    for (int off = 1; off < 64; off <<= 1) {
      a += __shfl_xor(a, off);
      b += __shfl_xor(b, off);
      c += __shfl_xor(c, off);
    }
    if (l == 0) { rspc[chunk] = a; sspc[chunk] = b; wspc[chunk] = c; }
  }
}

// ======================= ROUND-8 PIPELINE (best known: 169.8 µs) ====================

// Kernel 1b: B/Ext fragments for 32x32x16 MFMA
extern "C" __global__ void __launch_bounds__(256)
prep32_kernel(const short* __restrict__ x2bfT, const float* __restrict__ sqarr,
              short* __restrict__ Bfrag, short* __restrict__ Ext) {
  const int Sg = blockIdx.x;           // 512 groups of k=16
  const int t = threadIdx.x;
  const int q = t >> 6, l = t & 63;
  const int col = l & 31, kg = l >> 5;
  if (q < 2) {
    const bf16x8 v = *(const bf16x8*)(x2bfT + (size_t)(q * 32 + col) * NROWS + Sg * 16 + kg * 8);
    *(bf16x8*)(Bfrag + ((size_t)Sg * 2 + q) * 512 + l * 8) = v;
  } else if (q == 2) {
    bf16x8 e;
    if (col == 0) {
#pragma unroll
      for (int i = 0; i < 8; ++i) e[i] = (short)0x3F80;   // bf16 1.0
    } else if (col == 1) {
#pragma unroll
      for (int i = 0; i < 8; ++i) e[i] = f2bf(sqarr[Sg * 16 + kg * 8 + i]);
    } else {
#pragma unroll
      for (int i = 0; i < 8; ++i) e[i] = 0;
    }
    *(bf16x8*)(Ext + (size_t)Sg * 512 + l * 8) = e;
  }
}

#define LDG4(dst, ptr) \
  asm volatile("global_load_dwordx4 %0, %1, off" : "=&v"(dst) : "v"(ptr) : "memory")
#define VMCNTI(n) \
  do { asm volatile("s_waitcnt vmcnt(%0)" :: "i"(n) : "memory"); \
       __builtin_amdgcn_sched_barrier(0); } while (0)

extern "C" __global__ void __launch_bounds__(256, 2)
fused_lin_kernel(const float* __restrict__ A, const float* __restrict__ sarr,
                 const short* __restrict__ Bfrag, const short* __restrict__ Ext,
                 float* __restrict__ yp, float* __restrict__ rsp,
                 float* __restrict__ ssp, float* __restrict__ wsp,
                 int ks_shift, int nchunks) {
  __shared__ __attribute__((aligned(16))) short frag[4][8192];
  __shared__ __attribute__((aligned(16))) float sjbuf[2048];
  __shared__ float sibuf[128];

  const int t = threadIdx.x;
  const int l = t & 63;
  const int w = __builtin_amdgcn_readfirstlane(t >> 6);
  const int bid = blockIdx.x;
  const int js = bid & ((1 << ks_shift) - 1);
  const int rg = bid >> ks_shift;
  const int jspan = nchunks << 8;
  const int jb = js * jspan;
  const int rowbase = rg * 128 + w * 32;

  for (int k = t; k < jspan; k += 256) sjbuf[k] = sarr[jb + k];
  if (t < 128) sibuf[t] = sarr[rg * 128 + t];
  __syncthreads();

  short* myf = frag[w];
  char*  myfb = (char*)myf;
  const int s_l = l >> 2;
  const int hl32 = ((l >> 1) & 1) * 32;
  const int ssw = s_l & 7;
  const int ebase = s_l * 1024 + (l & 1) * 8;

  f32x16 accY0 = {}, accY1 = {}, accE = {}, accD = {};

#pragma unroll 1
  for (int ch = 0; ch < nchunks; ++ch) {
    const float* aBase = A + (size_t)rowbase * NROWS + jb + ch * 256 + (size_t)l * 4;
    f32x4 aval[8];
#pragma unroll
    for (int r = 0; r < 6; ++r) LDG4(aval[r & 7], aBase + (size_t)r * NROWS);
    const f32x4 sjv = *(const f32x4*)(sjbuf + ch * 256 + l * 4);
#pragma unroll
    for (int r = 0; r < 32; ++r) {
      if (r + 6 < 32) LDG4(aval[(r + 6) & 7], aBase + (size_t)(r + 6) * NROWS);
      VMCNTI((31 - r) < 6 ? (31 - r) : 6);
      const f32x4 a4 = aval[r & 7];
      const float si_r = sibuf[w * 32 + r];
      const float d0 = si_r - sjv[0], d1 = si_r - sjv[1];
      const float d2 = si_r - sjv[2], d3 = si_r - sjv[3];
      const float r0 = EXP2(fmaxf(d0, 0.1f * d0)) * a4[0];
      const float r1 = EXP2(fmaxf(d1, 0.1f * d1)) * a4[1];
      const float r2 = EXP2(fmaxf(d2, 0.1f * d2)) * a4[2];
      const float r3 = EXP2(fmaxf(d3, 0.1f * d3)) * a4[3];
      uint2 pk;
      pk.x = pack2(r0, r1);
      pk.y = pack2(r2, r3);
      *(uint2*)(myfb + ebase + ((((r + hl32) ^ ssw)) << 4)) = pk;
    }
    asm volatile("s_waitcnt lgkmcnt(0)" ::: "memory");
    __builtin_amdgcn_sched_barrier(0);

    const size_t Sg0 = (size_t)(jb >> 4) + (size_t)ch * 16;
    const short* bB = Bfrag + Sg0 * 1024 + l * 8;
    const short* eB = Ext + Sg0 * 512 + l * 8;
    bf16x8 rb0[4], rb1[4], re[4];
#pragma unroll
    for (int s = 0; s < 2; ++s) {
      LDG4(rb0[s], bB + s * 1024);
      LDG4(rb1[s], bB + s * 1024 + 512);
      LDG4(re[s],  eB + s * 512);
    }
#pragma unroll
    for (int s = 0; s < 16; ++s) {
      if (s + 2 < 16) {
        LDG4(rb0[(s + 2) & 3], bB + (s + 2) * 1024);
        LDG4(rb1[(s + 2) & 3], bB + (s + 2) * 1024 + 512);
        LDG4(re[(s + 2) & 3],  eB + (s + 2) * 512);
      }
      VMCNTI(3 * (15 - s) < 6 ? 3 * (15 - s) : 6);
      const bf16x8 ar = *(const bf16x8*)(myf + s * 512 + ((l ^ (s & 7)) << 3));
      accY0 = __builtin_amdgcn_mfma_f32_32x32x16_bf16(ar, rb0[s & 3], accY0, 0, 0, 0);
      accY1 = __builtin_amdgcn_mfma_f32_32x32x16_bf16(ar, rb1[s & 3], accY1, 0, 0, 0);
      accE  = __builtin_amdgcn_mfma_f32_32x32x16_bf16(ar, re[s & 3],  accE, 0, 0, 0);
      accD  = __builtin_amdgcn_mfma_f32_32x32x16_bf16(ar, ar,         accD, 0, 0, 0);
    }
  }

  float* ypb = yp + (size_t)js * NROWS * 64;
  const int cc = l & 31;
  const int rhi = (l >> 5) * 4;
#pragma unroll
  for (int reg = 0; reg < 16; ++reg) {
    const int rl = (reg & 3) + 8 * (reg >> 2) + rhi;
    const int grow = rowbase + rl;
    ypb[(size_t)grow * 64 + cc]      = accY0[reg];
    ypb[(size_t)grow * 64 + 32 + cc] = accY1[reg];
    if (cc == 0) rsp[js * NROWS + grow] = accE[reg];
    if (cc == 1) wsp[js * NROWS + grow] = accE[reg];
    if (rl == cc) ssp[js * NROWS + rowbase + cc] = accD[reg];
  }
}

extern "C" __global__ void __launch_bounds__(256)
finish_kernel(const float* __restrict__ x2, const float* __restrict__ sqarr,
              const float* __restrict__ yp, const float* __restrict__ rsp,
              const float* __restrict__ ssp, const float* __restrict__ wsp,
              const float* __restrict__ Wg, const float* __restrict__ bg,
              const float* __restrict__ W2, const float* __restrict__ b2,
              float* __restrict__ outp, float* __restrict__ l1c, float* __restrict__ l2c,
              int jsplit) {
  __shared__ float hbuf[4][64];
  __shared__ float gbuf[4][64];
  const int t = threadIdx.x;
  const int w = t >> 6, lane = t & 63;
  const int i = blockIdx.x * 4 + w;

  float yv = 0.f, rowsum = 0.f, sumsq = 0.f, wsq = 0.f;
#pragma unroll 4
  for (int p = 0; p < jsplit; ++p) {
    yv += yp[(size_t)p * NROWS * 64 + (size_t)i * 64 + lane];
    rowsum += rsp[p * NROWS + i];
    sumsq += ssp[p * NROWS + i];
    wsq += wsp[p * NROWS + i];
  }
  const float inv = 1.0f / rowsum;
  hbuf[w][lane] = yv * inv;
  const float xv = x2[(size_t)i * 64 + lane];
  float xy = xv * yv;
#pragma unroll
  for (int off = 1; off < 64; off <<= 1) xy += __shfl_xor(xy, off);
  if (lane == 0) {
    l1c[i] = sqarr[i] + (wsq - (2.0f / 64.0f) * xy) * inv;
    l2c[i] = sumsq * inv * inv;
  }
  __syncthreads();
  float accg = bg[lane];
  {
    const float* wrow = Wg + lane * 64;
#pragma unroll 4
    for (int d = 0; d < 64; ++d) accg = fmaf(wrow[d], hbuf[w][d], accg);
  }
  gbuf[w][lane] = leaky_f(accg);
  __syncthreads();
  if (lane < 32) {
    float acco = b2[lane];
    const float* wrow = W2 + lane * 64;
#pragma unroll 4
    for (int d = 0; d < 64; ++d) acco = fmaf(wrow[d], gbuf[w][d], acco);
    outp[(size_t)i * 32 + lane] = acco;
  }
}

extern "C" __global__ void __launch_bounds__(256)
loss_kernel(const float* __restrict__ l1c, const float* __restrict__ l2c,
            float* __restrict__ outp) {
  __shared__ float s1[256], s2[256];
  const int t = threadIdx.x;
  float a1 = 0.f, a2 = 0.f;
  for (int i = t * 4; i < NROWS; i += 1024) {
    const float4 v1 = *(const float4*)(l1c + i);
    const float4 v2 = *(const float4*)(l2c + i);
    a1 += (v1.x + v1.y) + (v1.z + v1.w);
    a2 += (v2.x + v2.y) + (v2.z + v2.w);
  }
  s1[t] = a1; s2[t] = a2;
  __syncthreads();
  for (int off = 128; off > 0; off >>= 1) {
    if (t < off) { s1[t] += s1[t + off]; s2[t] += s2[t + off]; }
    __syncthreads();
  }
  if (t == 0) {
    const float scale = 1.0f / ((float)NROWS * (float)NROWS);
    outp[NROWS * 32] = s1[0] * scale;
    outp[NROWS * 32 + 1] = s2[0] * scale;
  }
}

// ---------------- launch ------------------------------------------------------------
extern "C" void kernel_launch(void* const* d_in, const int* in_sizes, int n_in,
                              void* d_out, int out_size, void* d_ws, size_t ws_size,
                              hipStream_t stream) {
  const float* x   = (const float*)d_in[0];
  const float* A   = (const float*)d_in[1];
  const float* W10 = (const float*)d_in[2];
  const float* b10 = (const float*)d_in[3];
  const float* W11 = (const float*)d_in[4];
  const float* b11 = (const float*)d_in[5];
  const float* av  = (const float*)d_in[6];
  const float* Wg  = (const float*)d_in[7];
  const float* bg  = (const float*)d_in[8];
  const float* W2  = (const float*)d_in[9];
  const float* b2  = (const float*)d_in[10];
  float* out = (float*)d_out;

  const int ksplit = 8, ks_shift = 3;
  const int nchunks = (NROWS / ksplit) >> 8;   // 4

  // r8 pipeline layout (~25 MB)
  float* ws_f  = (float*)d_ws;
  float* x2    = ws_f;                                      // N*64
  float* sarr  = x2 + (size_t)NROWS * 64;                   // N
  float* sqarr = sarr + NROWS;                              // N
  float* yp    = sqarr + NROWS;                             // 8*N*64
  float* rsp   = yp + (size_t)ksplit * NROWS * 64;          // 8*N
  float* ssp   = rsp + (size_t)ksplit * NROWS;              // 8*N
  float* wsp   = ssp + (size_t)ksplit * NROWS;              // 8*N
  float* l1c   = wsp + (size_t)ksplit * NROWS;              // N
  float* l2c   = l1c + NROWS;                               // N
  short* x2bfT = (short*)(l2c + NROWS);                     // N*64 bf16
  short* Bfrag = x2bfT + (size_t)NROWS * 64;                // 512*1024 bf16
  short* Ext   = Bfrag + (size_t)512 * 1024;                // 512*512 bf16
  // calibration scratch
  float* osumA = (float*)(Ext + (size_t)512 * 512);         // 2048
  float* osumB = osumA + 2048;                              // 2048
  float* rspc  = osumB + 2048;                              // 262144
  float* sspc  = rspc + 262144;                             // 262144
  float* wspc  = sspc + 262144;                             // 262144
  short* raw   = (short*)(wspc + 262144);                   // N*N bf16 (128MB)
  const size_t need_conv = ((char*)(raw + (size_t)NROWS * NROWS) - (char*)d_ws);

  hipLaunchKernelGGL(encoder_kernel, dim3(2048), dim3(256), 0, stream,
                     x, W10, b10, W11, b11, av, x2, sarr, sqarr, x2bfT);

  // calibration ladder (outputs unused by the real pipeline)
  hipLaunchKernelGGL(readbench_kernel, dim3(2048), dim3(256), 0, stream, A, osumA);
  hipLaunchKernelGGL(expbench_kernel, dim3(2048), dim3(256), 0, stream,
                     A, sarr, sqarr, osumB);
  if (ws_size >= need_conv)
    hipLaunchKernelGGL(convbench_kernel, dim3(2048), dim3(256), 0, stream,
                       A, sarr, sqarr, raw, rspc, sspc, wspc);

  // real pipeline (round 8)
  hipLaunchKernelGGL(prep32_kernel, dim3(512), dim3(256), 0, stream,
                     x2bfT, sqarr, Bfrag, Ext);
  hipLaunchKernelGGL(fused_lin_kernel, dim3(64 * ksplit), dim3(256), 0, stream,
                     A, sarr, Bfrag, Ext, yp, rsp, ssp, wsp, ks_shift, nchunks);
  hipLaunchKernelGGL(finish_kernel, dim3(2048), dim3(256), 0, stream,
                     x2, sqarr, yp, rsp, ssp, wsp, Wg, bg, W2, b2, out, l1c, l2c, ksplit);
  hipLaunchKernelGGL(loss_kernel, dim3(1), dim3(256), 0, stream, l1c, l2c, out);
}

// Round 13
// 277.654 us; speedup vs baseline: 1.3716x; 1.3716x over previous
//
#include <hip/hip_runtime.h>
#include <hip/hip_bf16.h>
#include <cstddef>
#include <cstdint>

#define NROWS 8192
#define LOG2E 1.4426950408889634f

typedef __attribute__((ext_vector_type(8))) short bf16x8;
typedef __attribute__((ext_vector_type(4))) float f32x4;

#define EXP2(x) __builtin_amdgcn_exp2f(x)

__device__ __forceinline__ short f2bf(float f) {
  unsigned u = __float_as_uint(f);
  u += 0x7fffu + ((u >> 16) & 1u);   // RNE
  return (short)(u >> 16);
}
__device__ __forceinline__ float leaky_f(float v) { return fmaxf(v, 0.1f * v); }

union BFPair { __hip_bfloat162 h; unsigned u; };
__device__ __forceinline__ unsigned pack2(float a, float b) {
  BFPair p;
  p.h = __float22bfloat162_rn(make_float2(a, b));  // v_cvt_pk_bf16_f32
  return p.u;
}
__device__ __forceinline__ f32x4 ntload4(const float* p) {
  return __builtin_nontemporal_load((const f32x4*)p);   // bypass L3 alloc: keep L3 for rawfrag
}

// ---------------- Kernel 1: MLP encoder: x[8192,256] -> x2, s(prescaled), sq, x2bfT --
extern "C" __global__ void __launch_bounds__(256)
encoder_kernel(const float* __restrict__ x, const float* __restrict__ W10,
               const float* __restrict__ b10, const float* __restrict__ W11,
               const float* __restrict__ b11, const float* __restrict__ avec,
               float* __restrict__ x2, float* __restrict__ sarr,
               float* __restrict__ sqarr, short* __restrict__ x2bfT) {
  __shared__ float xr[4][256];
  __shared__ float h1[4][128];
  const int t = threadIdx.x;
  const int r0 = blockIdx.x * 4;
#pragma unroll
  for (int r = 0; r < 4; ++r) xr[r][t] = x[(size_t)(r0 + r) * 256 + t];
  __syncthreads();
  if (t < 128) {
    float acc[4];
    const float b = b10[t];
#pragma unroll
    for (int r = 0; r < 4; ++r) acc[r] = b;
    const float* wrow = W10 + t * 256;
    for (int c = 0; c < 256; c += 4) {
      const float4 wv = *(const float4*)(wrow + c);
#pragma unroll
      for (int r = 0; r < 4; ++r) {
        acc[r] = fmaf(wv.x, xr[r][c], acc[r]);
        acc[r] = fmaf(wv.y, xr[r][c + 1], acc[r]);
        acc[r] = fmaf(wv.z, xr[r][c + 2], acc[r]);
        acc[r] = fmaf(wv.w, xr[r][c + 3], acc[r]);
      }
    }
#pragma unroll
    for (int r = 0; r < 4; ++r) h1[r][t] = leaky_f(acc[r]);
  }
  __syncthreads();
  if (t < 64) {
    float acc[4];
    const float b = b11[t];
#pragma unroll
    for (int r = 0; r < 4; ++r) acc[r] = b;
    const float* wrow = W11 + t * 128;
    for (int c = 0; c < 128; c += 4) {
      const float4 wv = *(const float4*)(wrow + c);
#pragma unroll
      for (int r = 0; r < 4; ++r) {
        acc[r] = fmaf(wv.x, h1[r][c], acc[r]);
        acc[r] = fmaf(wv.y, h1[r][c + 1], acc[r]);
        acc[r] = fmaf(wv.z, h1[r][c + 2], acc[r]);
        acc[r] = fmaf(wv.w, h1[r][c + 3], acc[r]);
      }
    }
    const float av = avec[t];
#pragma unroll
    for (int r = 0; r < 4; ++r) {
      const float v = leaky_f(acc[r]);
      x2[(size_t)(r0 + r) * 64 + t] = v;
      x2bfT[(size_t)t * NROWS + r0 + r] = f2bf(v);
      float ps = v * av, pq = v * v;
#pragma unroll
      for (int off = 1; off < 64; off <<= 1) {
        ps += __shfl_xor(ps, off);
        pq += __shfl_xor(pq, off);
      }
      if (t == 0) {
        sarr[r0 + r] = ps * LOG2E;          // exp(leaky(d)) = exp2(leaky(d*log2e))
        sqarr[r0 + r] = pq * (1.0f / 64.0f);
      }
    }
  }
}

// ---------------- Kernel 1b: B fragments (16x16x32 layout, contiguous) --------------
// Bfrag[S][nf][lane][8]: x2^T[n = nf*16 + (lane&15)][k = S*32 + (lane>>4)*8 + e]
extern "C" __global__ void __launch_bounds__(256)
prep16_kernel(const short* __restrict__ x2bfT, short* __restrict__ Bfrag) {
  const int S = blockIdx.x;           // 256 k-groups of 32
  const int t = threadIdx.x;
  const int nf = t >> 6, l = t & 63;
  const bf16x8 v = *(const bf16x8*)(x2bfT + (size_t)(nf * 16 + (l & 15)) * NROWS
                                    + S * 32 + (l >> 4) * 8);
  *(bf16x8*)(Bfrag + ((size_t)S * 4 + nf) * 512 + l * 8) = v;
}

// ---------------- Kernel 2: DENSE-SWEEP convert (validated read side, r12 convbench) -
// Wave gw handles 1KB chunks {gw + k*8192} — chip-wide dense 8MB window. Per chunk:
// 1KB contiguous nt-read of A, exp2/leaky, exact fp32 chunk partials (fixed slots),
// and an 8B/lane scatter-store straight into MFMA A-fragment order. Rows of one
// 16-row group map to bids ≡ (mod 8) -> the 16B segments of each 128B line assemble
// within ONE XCD's L2 (no cross-XCD line sharing).
extern "C" __global__ void __launch_bounds__(256)
convert_kernel(const float* __restrict__ A, const float* __restrict__ sarr,
               const float* __restrict__ sqarr, short* __restrict__ rawfrag,
               float* __restrict__ rspc, float* __restrict__ sspc,
               float* __restrict__ wspc) {
  const int t = threadIdx.x, l = t & 63, w = t >> 6;
  const int gw = blockIdx.x * 4 + w;          // 0..8191
  // lane-constant pieces of the fragment address:
  const int S_local = l >> 3;                 // 0..7   (S-tile within chunk)
  const int kg = (l >> 1) & 3;                // 0..3   (8-col granule within tile)
  const int h = l & 1;                        // 0/1    (4-col half of granule)
#pragma unroll 1
  for (int k = 0; k < 32; ++k) {
    const int chunk = gw + k * 8192;          // dense sweep
    const int i = chunk >> 5;                 // row
    const int cc = chunk & 31;                // col-chunk (256 cols)
    const int rt = i >> 4, fr = i & 15;
    const int jc = cc << 8;
    const float sif = sarr[i];
    const f32x4 a4 = ntload4(A + (size_t)chunk * 256 + l * 4);
    const f32x4 sj = *(const f32x4*)(sarr + jc + l * 4);
    const f32x4 sq = *(const f32x4*)(sqarr + jc + l * 4);
    const float d0 = sif - sj[0], d1 = sif - sj[1];
    const float d2 = sif - sj[2], d3 = sif - sj[3];
    const float r0 = EXP2(fmaxf(d0, 0.1f * d0)) * a4[0];
    const float r1 = EXP2(fmaxf(d1, 0.1f * d1)) * a4[1];
    const float r2 = EXP2(fmaxf(d2, 0.1f * d2)) * a4[2];
    const float r3 = EXP2(fmaxf(d3, 0.1f * d3)) * a4[3];
    uint2 pk;
    pk.x = pack2(r0, r1);
    pk.y = pack2(r2, r3);
    // fragment store: tile (rt, S = cc*8 + S_local), entry kg*16 + fr, half h
    const size_t soff = (((size_t)rt * 256 + cc * 8 + S_local) * 64
                         + kg * 16 + fr) * 8 + h * 4;    // in shorts
    *(uint2*)(rawfrag + soff) = pk;
    float a = (r0 + r1) + (r2 + r3);
    float b = fmaf(r0, r0, fmaf(r1, r1, fmaf(r2, r2, r3 * r3)));
    float c = fmaf(r0, sq[0], fmaf(r1, sq[1], fmaf(r2, sq[2], r3 * sq[3])));
#pragma unroll
    for (int off = 1; off < 64; off <<= 1) {
      a += __shfl_xor(a, off);
      b += __shfl_xor(b, off);
      c += __shfl_xor(c, off);
    }
    if (l == 0) { rspc[chunk] = a; sspc[chunk] = b; wspc[chunk] = c; }
  }
}

// ---------------- Kernel 2b: fold 32 chunk-partials per row into exact scalars ------
extern "C" __global__ void __launch_bounds__(256)
rowreduce_kernel(const float* __restrict__ rspc, const float* __restrict__ sspc,
                 const float* __restrict__ wspc, float* __restrict__ rs,
                 float* __restrict__ ss, float* __restrict__ ws) {
  const int i = blockIdx.x * 256 + threadIdx.x;   // 8192 rows
  float a = 0.f, b = 0.f, c = 0.f;
#pragma unroll
  for (int q = 0; q < 32; ++q) {
    a += rspc[i * 32 + q];
    b += sspc[i * 32 + q];
    c += wspc[i * 32 + q];
  }
  rs[i] = a; ss[i] = b; ws[i] = c;
}

// ---------------- Kernel 3: linear-stream MFMA GEMM over fragment-ordered raw -------
// 2048 blocks (8/CU). Block (rt, q); wave w owns S-range q*64 + w*16 .. +16:
// A-panel = 16KB CONTIGUOUS stream; Bfrag 4KB/step (1MB total, L2-hot); 4 MFMA/step.
// Plain compiler-scheduled loads, no manual waits, no LDS.
extern "C" __global__ void __launch_bounds__(256)
gemm16_kernel(const short* __restrict__ rawfrag, const short* __restrict__ Bfrag,
              float* __restrict__ yp) {
  const int t = threadIdx.x, l = t & 63, w = t >> 6;
  const int rt = blockIdx.x >> 2;
  const int q = blockIdx.x & 3;
  const int S0 = q * 64 + w * 16;
  const short* ap = rawfrag + ((size_t)rt * 256 + S0) * 512 + l * 8;
  const short* bp = Bfrag + (size_t)S0 * 2048 + l * 8;

  f32x4 acc0 = {0.f,0.f,0.f,0.f}, acc1 = {0.f,0.f,0.f,0.f};
  f32x4 acc2 = {0.f,0.f,0.f,0.f}, acc3 = {0.f,0.f,0.f,0.f};
#pragma unroll
  for (int s = 0; s < 16; ++s) {
    const bf16x8 ar = *(const bf16x8*)(ap + s * 512);
    const short* bs = bp + (size_t)s * 2048;
    const bf16x8 b0 = *(const bf16x8*)(bs);
    const bf16x8 b1 = *(const bf16x8*)(bs + 512);
    const bf16x8 b2 = *(const bf16x8*)(bs + 1024);
    const bf16x8 b3 = *(const bf16x8*)(bs + 1536);
    acc0 = __builtin_amdgcn_mfma_f32_16x16x32_bf16(ar, b0, acc0, 0, 0, 0);
    acc1 = __builtin_amdgcn_mfma_f32_16x16x32_bf16(ar, b1, acc1, 0, 0, 0);
    acc2 = __builtin_amdgcn_mfma_f32_16x16x32_bf16(ar, b2, acc2, 0, 0, 0);
    acc3 = __builtin_amdgcn_mfma_f32_16x16x32_bf16(ar, b3, acc3, 0, 0, 0);
  }
  // C/D layout: col = lane&15, row = (lane>>4)*4 + reg; partial p = q*4 + w
  float* ypb = yp + (size_t)(q * 4 + w) * NROWS * 64;
  const int fr = l & 15, kg = l >> 4;
  const f32x4 accs[4] = {acc0, acc1, acc2, acc3};
#pragma unroll
  for (int nf = 0; nf < 4; ++nf)
#pragma unroll
    for (int ri = 0; ri < 4; ++ri)
      ypb[(size_t)(rt * 16 + kg * 4 + ri) * 64 + nf * 16 + fr] = accs[nf][ri];
}

// ---------------- Kernel 4: combine partials, GNN layer + head, per-row losses ------
extern "C" __global__ void __launch_bounds__(256)
finish_kernel(const float* __restrict__ x2, const float* __restrict__ sqarr,
              const float* __restrict__ yp, const float* __restrict__ rs,
              const float* __restrict__ ss, const float* __restrict__ ws,
              const float* __restrict__ Wg, const float* __restrict__ bg,
              const float* __restrict__ W2, const float* __restrict__ b2,
              float* __restrict__ outp, float* __restrict__ l1c, float* __restrict__ l2c) {
  __shared__ float hbuf[4][64];
  __shared__ float gbuf[4][64];
  const int t = threadIdx.x;
  const int w = t >> 6, lane = t & 63;
  const int i = blockIdx.x * 4 + w;

  float yv = 0.f;
#pragma unroll
  for (int p = 0; p < 16; ++p)
    yv += yp[(size_t)p * NROWS * 64 + (size_t)i * 64 + lane];
  const float rowsum = rs[i], sumsq = ss[i], wsq = ws[i];
  const float inv = 1.0f / rowsum;
  hbuf[w][lane] = yv * inv;
  const float xv = x2[(size_t)i * 64 + lane];
  float xy = xv * yv;
#pragma unroll
  for (int off = 1; off < 64; off <<= 1) xy += __shfl_xor(xy, off);
  if (lane == 0) {
    l1c[i] = sqarr[i] + (wsq - (2.0f / 64.0f) * xy) * inv;
    l2c[i] = sumsq * inv * inv;
  }
  __syncthreads();
  float accg = bg[lane];
  {
    const float* wrow = Wg + lane * 64;
#pragma unroll 4
    for (int d = 0; d < 64; ++d) accg = fmaf(wrow[d], hbuf[w][d], accg);
  }
  gbuf[w][lane] = leaky_f(accg);
  __syncthreads();
  if (lane < 32) {
    float acco = b2[lane];
    const float* wrow = W2 + lane * 64;
#pragma unroll 4
    for (int d = 0; d < 64; ++d) acco = fmaf(wrow[d], gbuf[w][d], acco);
    outp[(size_t)i * 32 + lane] = acco;
  }
}

// ---------------- Kernel 5: scalar loss reduction -----------------------------------
extern "C" __global__ void __launch_bounds__(256)
loss_kernel(const float* __restrict__ l1c, const float* __restrict__ l2c,
            float* __restrict__ outp) {
  __shared__ float s1[256], s2[256];
  const int t = threadIdx.x;
  float a1 = 0.f, a2 = 0.f;
  for (int i = t * 4; i < NROWS; i += 1024) {
    const float4 v1 = *(const float4*)(l1c + i);
    const float4 v2 = *(const float4*)(l2c + i);
    a1 += (v1.x + v1.y) + (v1.z + v1.w);
    a2 += (v2.x + v2.y) + (v2.z + v2.w);
  }
  s1[t] = a1; s2[t] = a2;
  __syncthreads();
  for (int off = 128; off > 0; off >>= 1) {
    if (t < off) { s1[t] += s1[t + off]; s2[t] += s2[t + off]; }
    __syncthreads();
  }
  if (t == 0) {
    const float scale = 1.0f / ((float)NROWS * (float)NROWS);
    outp[NROWS * 32] = s1[0] * scale;
    outp[NROWS * 32 + 1] = s2[0] * scale;
  }
}

// ---------------- launch ------------------------------------------------------------
extern "C" void kernel_launch(void* const* d_in, const int* in_sizes, int n_in,
                              void* d_out, int out_size, void* d_ws, size_t ws_size,
                              hipStream_t stream) {
  const float* x   = (const float*)d_in[0];
  const float* A   = (const float*)d_in[1];
  const float* W10 = (const float*)d_in[2];
  const float* b10 = (const float*)d_in[3];
  const float* W11 = (const float*)d_in[4];
  const float* b11 = (const float*)d_in[5];
  const float* av  = (const float*)d_in[6];
  const float* Wg  = (const float*)d_in[7];
  const float* bg  = (const float*)d_in[8];
  const float* W2  = (const float*)d_in[9];
  const float* b2  = (const float*)d_in[10];
  float* out = (float*)d_out;

  // workspace layout (~175 MB; proven available in r9/r11)
  float* ws_f  = (float*)d_ws;
  float* x2    = ws_f;                                 // N*64
  float* sarr  = x2 + (size_t)NROWS * 64;              // N (prescaled by log2e)
  float* sqarr = sarr + NROWS;                         // N
  float* l1c   = sqarr + NROWS;                        // N
  float* l2c   = l1c + NROWS;                          // N
  float* rs    = l2c + NROWS;                          // N
  float* ssum  = rs + NROWS;                           // N
  float* wsq   = ssum + NROWS;                         // N
  float* rspc  = wsq + NROWS;                          // 262144
  float* sspc  = rspc + 262144;                        // 262144
  float* wspc  = sspc + 262144;                        // 262144
  float* yp    = wspc + 262144;                        // 16*N*64
  short* x2bfT = (short*)(yp + (size_t)16 * NROWS * 64);   // N*64
  short* Bfrag = x2bfT + (size_t)NROWS * 64;           // 256*2048
  short* rawfrag = Bfrag + (size_t)256 * 2048;         // N*N bf16 (128 MB, frag order)

  hipLaunchKernelGGL(encoder_kernel, dim3(2048), dim3(256), 0, stream,
                     x, W10, b10, W11, b11, av, x2, sarr, sqarr, x2bfT);
  hipLaunchKernelGGL(prep16_kernel, dim3(256), dim3(256), 0, stream, x2bfT, Bfrag);
  hipLaunchKernelGGL(convert_kernel, dim3(2048), dim3(256), 0, stream,
                     A, sarr, sqarr, rawfrag, rspc, sspc, wspc);
  hipLaunchKernelGGL(rowreduce_kernel, dim3(32), dim3(256), 0, stream,
                     rspc, sspc, wspc, rs, ssum, wsq);
  hipLaunchKernelGGL(gemm16_kernel, dim3(2048), dim3(256), 0, stream,
                     rawfrag, Bfrag, yp);
  hipLaunchKernelGGL(finish_kernel, dim3(2048), dim3(256), 0, stream,
                     x2, sqarr, yp, rs, ssum, wsq, Wg, bg, W2, b2, out, l1c, l2c);
  hipLaunchKernelGGL(loss_kernel, dim3(1), dim3(256), 0, stream, l1c, l2c, out);
}

// Round 14
// 240.789 us; speedup vs baseline: 1.5815x; 1.1531x over previous
//
#include <hip/hip_runtime.h>
#include <hip/hip_bf16.h>
#include <cstddef>
#include <cstdint>

#define NROWS 8192
#define LOG2E 1.4426950408889634f

typedef __attribute__((ext_vector_type(8))) short bf16x8;
typedef __attribute__((ext_vector_type(4))) float f32x4;

#define EXP2(x) __builtin_amdgcn_exp2f(x)

__device__ __forceinline__ short f2bf(float f) {
  unsigned u = __float_as_uint(f);
  u += 0x7fffu + ((u >> 16) & 1u);   // RNE
  return (short)(u >> 16);
}
__device__ __forceinline__ float leaky_f(float v) { return fmaxf(v, 0.1f * v); }

union BFPair { __hip_bfloat162 h; unsigned u; };
__device__ __forceinline__ unsigned pack2(float a, float b) {
  BFPair p;
  p.h = __float22bfloat162_rn(make_float2(a, b));  // v_cvt_pk_bf16_f32
  return p.u;
}
__device__ __forceinline__ f32x4 ntload4(const float* p) {
  return __builtin_nontemporal_load((const f32x4*)p);   // keep L3 for raw
}

// ---------------- Kernel 1: MLP encoder: x[8192,256] -> x2, s(prescaled), sq, x2bfT --
extern "C" __global__ void __launch_bounds__(256)
encoder_kernel(const float* __restrict__ x, const float* __restrict__ W10,
               const float* __restrict__ b10, const float* __restrict__ W11,
               const float* __restrict__ b11, const float* __restrict__ avec,
               float* __restrict__ x2, float* __restrict__ sarr,
               float* __restrict__ sqarr, short* __restrict__ x2bfT) {
  __shared__ float xr[4][256];
  __shared__ float h1[4][128];
  const int t = threadIdx.x;
  const int r0 = blockIdx.x * 4;
#pragma unroll
  for (int r = 0; r < 4; ++r) xr[r][t] = x[(size_t)(r0 + r) * 256 + t];
  __syncthreads();
  if (t < 128) {
    float acc[4];
    const float b = b10[t];
#pragma unroll
    for (int r = 0; r < 4; ++r) acc[r] = b;
    const float* wrow = W10 + t * 256;
    for (int c = 0; c < 256; c += 4) {
      const float4 wv = *(const float4*)(wrow + c);
#pragma unroll
      for (int r = 0; r < 4; ++r) {
        acc[r] = fmaf(wv.x, xr[r][c], acc[r]);
        acc[r] = fmaf(wv.y, xr[r][c + 1], acc[r]);
        acc[r] = fmaf(wv.z, xr[r][c + 2], acc[r]);
        acc[r] = fmaf(wv.w, xr[r][c + 3], acc[r]);
      }
    }
#pragma unroll
    for (int r = 0; r < 4; ++r) h1[r][t] = leaky_f(acc[r]);
  }
  __syncthreads();
  if (t < 64) {
    float acc[4];
    const float b = b11[t];
#pragma unroll
    for (int r = 0; r < 4; ++r) acc[r] = b;
    const float* wrow = W11 + t * 128;
    for (int c = 0; c < 128; c += 4) {
      const float4 wv = *(const float4*)(wrow + c);
#pragma unroll
      for (int r = 0; r < 4; ++r) {
        acc[r] = fmaf(wv.x, h1[r][c], acc[r]);
        acc[r] = fmaf(wv.y, h1[r][c + 1], acc[r]);
        acc[r] = fmaf(wv.z, h1[r][c + 2], acc[r]);
        acc[r] = fmaf(wv.w, h1[r][c + 3], acc[r]);
      }
    }
    const float av = avec[t];
#pragma unroll
    for (int r = 0; r < 4; ++r) {
      const float v = leaky_f(acc[r]);
      x2[(size_t)(r0 + r) * 64 + t] = v;
      x2bfT[(size_t)t * NROWS + r0 + r] = f2bf(v);
      float ps = v * av, pq = v * v;
#pragma unroll
      for (int off = 1; off < 64; off <<= 1) {
        ps += __shfl_xor(ps, off);
        pq += __shfl_xor(pq, off);
      }
      if (t == 0) {
        sarr[r0 + r] = ps * LOG2E;          // exp(leaky(d)) = exp2(leaky(d*log2e))
        sqarr[r0 + r] = pq * (1.0f / 64.0f);
      }
    }
  }
}

// ---------------- Kernel 1b: B fragments (16x16x32 layout, contiguous) --------------
// Bfrag[S][nf][lane][8]: x2^T[n = nf*16 + (lane&15)][k = S*32 + (lane>>4)*8 + e]
extern "C" __global__ void __launch_bounds__(256)
prep16_kernel(const short* __restrict__ x2bfT, short* __restrict__ Bfrag) {
  const int S = blockIdx.x;           // 256 k-groups of 32
  const int t = threadIdx.x;
  const int nf = t >> 6, l = t & 63;
  const bf16x8 v = *(const bf16x8*)(x2bfT + (size_t)(nf * 16 + (l & 15)) * NROWS
                                    + S * 32 + (l >> 4) * 8);
  *(bf16x8*)(Bfrag + ((size_t)S * 4 + nf) * 512 + l * 8) = v;
}

// ---------------- Kernel 2: DENSE-SWEEP convert — r12 convbench VERBATIM ------------
// (validated fast: ~70us). 1KB contiguous nt-read of A per wave-instr, exp2/leaky,
// 512B contiguous row-major bf16 store, exact fp32 chunk partials to fixed slots.
extern "C" __global__ void __launch_bounds__(256)
convert_kernel(const float* __restrict__ A, const float* __restrict__ sarr,
               const float* __restrict__ sqarr, short* __restrict__ raw,
               float* __restrict__ rspc, float* __restrict__ sspc,
               float* __restrict__ wspc) {
  const int t = threadIdx.x, l = t & 63, w = t >> 6;
  const int gw = blockIdx.x * 4 + w;          // 0..8191
#pragma unroll 1
  for (int k = 0; k < 32; ++k) {
    const int chunk = gw + k * 8192;
    const int i = chunk >> 5;
    const int jc = (chunk & 31) << 8;
    const float sif = sarr[i];
    const f32x4 a4 = ntload4(A + (size_t)chunk * 256 + l * 4);
    const f32x4 sj = *(const f32x4*)(sarr + jc + l * 4);
    const f32x4 sq = *(const f32x4*)(sqarr + jc + l * 4);
    const float d0 = sif - sj[0], d1 = sif - sj[1];
    const float d2 = sif - sj[2], d3 = sif - sj[3];
    const float r0 = EXP2(fmaxf(d0, 0.1f * d0)) * a4[0];
    const float r1 = EXP2(fmaxf(d1, 0.1f * d1)) * a4[1];
    const float r2 = EXP2(fmaxf(d2, 0.1f * d2)) * a4[2];
    const float r3 = EXP2(fmaxf(d3, 0.1f * d3)) * a4[3];
    uint2 pk;
    pk.x = pack2(r0, r1);
    pk.y = pack2(r2, r3);
    *(uint2*)(raw + (size_t)chunk * 256 + l * 4) = pk;   // 512B/wave contiguous
    float a = (r0 + r1) + (r2 + r3);
    float b = fmaf(r0, r0, fmaf(r1, r1, fmaf(r2, r2, r3 * r3)));
    float c = fmaf(r0, sq[0], fmaf(r1, sq[1], fmaf(r2, sq[2], r3 * sq[3])));
#pragma unroll
    for (int off = 1; off < 64; off <<= 1) {
      a += __shfl_xor(a, off);
      b += __shfl_xor(b, off);
      c += __shfl_xor(c, off);
    }
    if (l == 0) { rspc[chunk] = a; sspc[chunk] = b; wspc[chunk] = c; }
  }
}

// ---------------- Kernel 2b: fold 32 chunk-partials per row into exact scalars ------
extern "C" __global__ void __launch_bounds__(256)
rowreduce_kernel(const float* __restrict__ rspc, const float* __restrict__ sspc,
                 const float* __restrict__ wspc, float* __restrict__ rs,
                 float* __restrict__ ss, float* __restrict__ ws) {
  const int i = blockIdx.x * 256 + threadIdx.x;   // 8192 rows
  float a = 0.f, b = 0.f, c = 0.f;
#pragma unroll
  for (int q = 0; q < 32; ++q) {
    a += rspc[i * 32 + q];
    b += sspc[i * 32 + q];
    c += wspc[i * 32 + q];
  }
  rs[i] = a; ss[i] = b; ws[i] = c;
}

// ---------------- Kernel 3: GEMM over row-major raw via 4KB-contiguous LDS staging --
// Block (rg, c): rows rg*16..+16, cols c*2048..+2048. Stage = 16 instructions, each a
// 4KB fully-contiguous read of L3-resident raw -> padded LDS. One barrier. Wave w
// handles S-tiles c*64 + w*16 .. +16: A-frag ds_read_b128 (2-way bank alias = free),
// Bfrag L2-hot, 4 MFMA/step. Partial p = c*4 + w (16 partials, summed in finish).
extern "C" __global__ void __launch_bounds__(256)
gemm_lds_kernel(const short* __restrict__ raw, const short* __restrict__ Bfrag,
                float* __restrict__ yp) {
  __shared__ __attribute__((aligned(16))) short stage[16][2056];   // 4112B rows
  const int t = threadIdx.x, l = t & 63, w = t >> 6;
  const int rg = blockIdx.x >> 2;          // 0..511
  const int c = blockIdx.x & 3;            // col-slice (2048 cols)
  const int row0 = rg * 16;

  // stage: 16 x 4KB contiguous reads (256 threads x 16B each)
#pragma unroll
  for (int r = 0; r < 16; ++r) {
    const bf16x8 v = *(const bf16x8*)(raw + (size_t)(row0 + r) * NROWS
                                      + c * 2048 + t * 8);
    *(bf16x8*)(&stage[r][t * 8]) = v;
  }
  __syncthreads();

  const int fr = l & 15, kg = l >> 4;
  f32x4 acc0 = {0.f,0.f,0.f,0.f}, acc1 = {0.f,0.f,0.f,0.f};
  f32x4 acc2 = {0.f,0.f,0.f,0.f}, acc3 = {0.f,0.f,0.f,0.f};

  const short* bp = Bfrag + (size_t)(c * 64 + w * 16) * 2048 + l * 8;
#pragma unroll
  for (int s = 0; s < 16; ++s) {
    const bf16x8 ar = *(const bf16x8*)(&stage[fr][w * 512 + s * 32 + kg * 8]);
    const short* bs = bp + (size_t)s * 2048;
    const bf16x8 b0 = *(const bf16x8*)(bs);
    const bf16x8 b1 = *(const bf16x8*)(bs + 512);
    const bf16x8 b2 = *(const bf16x8*)(bs + 1024);
    const bf16x8 b3 = *(const bf16x8*)(bs + 1536);
    acc0 = __builtin_amdgcn_mfma_f32_16x16x32_bf16(ar, b0, acc0, 0, 0, 0);
    acc1 = __builtin_amdgcn_mfma_f32_16x16x32_bf16(ar, b1, acc1, 0, 0, 0);
    acc2 = __builtin_amdgcn_mfma_f32_16x16x32_bf16(ar, b2, acc2, 0, 0, 0);
    acc3 = __builtin_amdgcn_mfma_f32_16x16x32_bf16(ar, b3, acc3, 0, 0, 0);
  }
  // C/D layout: col = lane&15, row = (lane>>4)*4 + reg; partial p = c*4 + w
  float* ypb = yp + (size_t)(c * 4 + w) * NROWS * 64;
  const f32x4 accs[4] = {acc0, acc1, acc2, acc3};
#pragma unroll
  for (int nf = 0; nf < 4; ++nf)
#pragma unroll
    for (int ri = 0; ri < 4; ++ri)
      ypb[(size_t)(row0 + kg * 4 + ri) * 64 + nf * 16 + fr] = accs[nf][ri];
}

// ---------------- Kernel 4: combine partials, GNN layer + head, per-row losses ------
extern "C" __global__ void __launch_bounds__(256)
finish_kernel(const float* __restrict__ x2, const float* __restrict__ sqarr,
              const float* __restrict__ yp, const float* __restrict__ rs,
              const float* __restrict__ ss, const float* __restrict__ ws,
              const float* __restrict__ Wg, const float* __restrict__ bg,
              const float* __restrict__ W2, const float* __restrict__ b2,
              float* __restrict__ outp, float* __restrict__ l1c, float* __restrict__ l2c) {
  __shared__ float hbuf[4][64];
  __shared__ float gbuf[4][64];
  const int t = threadIdx.x;
  const int w = t >> 6, lane = t & 63;
  const int i = blockIdx.x * 4 + w;

  float yv = 0.f;
#pragma unroll
  for (int p = 0; p < 16; ++p)
    yv += yp[(size_t)p * NROWS * 64 + (size_t)i * 64 + lane];
  const float rowsum = rs[i], sumsq = ss[i], wsq = ws[i];
  const float inv = 1.0f / rowsum;
  hbuf[w][lane] = yv * inv;
  const float xv = x2[(size_t)i * 64 + lane];
  float xy = xv * yv;
#pragma unroll
  for (int off = 1; off < 64; off <<= 1) xy += __shfl_xor(xy, off);
  if (lane == 0) {
    l1c[i] = sqarr[i] + (wsq - (2.0f / 64.0f) * xy) * inv;
    l2c[i] = sumsq * inv * inv;
  }
  __syncthreads();
  float accg = bg[lane];
  {
    const float* wrow = Wg + lane * 64;
#pragma unroll 4
    for (int d = 0; d < 64; ++d) accg = fmaf(wrow[d], hbuf[w][d], accg);
  }
  gbuf[w][lane] = leaky_f(accg);
  __syncthreads();
  if (lane < 32) {
    float acco = b2[lane];
    const float* wrow = W2 + lane * 64;
#pragma unroll 4
    for (int d = 0; d < 64; ++d) acco = fmaf(wrow[d], gbuf[w][d], acco);
    outp[(size_t)i * 32 + lane] = acco;
  }
}

// ---------------- Kernel 5: scalar loss reduction -----------------------------------
extern "C" __global__ void __launch_bounds__(256)
loss_kernel(const float* __restrict__ l1c, const float* __restrict__ l2c,
            float* __restrict__ outp) {
  __shared__ float s1[256], s2[256];
  const int t = threadIdx.x;
  float a1 = 0.f, a2 = 0.f;
  for (int i = t * 4; i < NROWS; i += 1024) {
    const float4 v1 = *(const float4*)(l1c + i);
    const float4 v2 = *(const float4*)(l2c + i);
    a1 += (v1.x + v1.y) + (v1.z + v1.w);
    a2 += (v2.x + v2.y) + (v2.z + v2.w);
  }
  s1[t] = a1; s2[t] = a2;
  __syncthreads();
  for (int off = 128; off > 0; off >>= 1) {
    if (t < off) { s1[t] += s1[t + off]; s2[t] += s2[t + off]; }
    __syncthreads();
  }
  if (t == 0) {
    const float scale = 1.0f / ((float)NROWS * (float)NROWS);
    outp[NROWS * 32] = s1[0] * scale;
    outp[NROWS * 32 + 1] = s2[0] * scale;
  }
}

// ---------------- launch ------------------------------------------------------------
extern "C" void kernel_launch(void* const* d_in, const int* in_sizes, int n_in,
                              void* d_out, int out_size, void* d_ws, size_t ws_size,
                              hipStream_t stream) {
  const float* x   = (const float*)d_in[0];
  const float* A   = (const float*)d_in[1];
  const float* W10 = (const float*)d_in[2];
  const float* b10 = (const float*)d_in[3];
  const float* W11 = (const float*)d_in[4];
  const float* b11 = (const float*)d_in[5];
  const float* av  = (const float*)d_in[6];
  const float* Wg  = (const float*)d_in[7];
  const float* bg  = (const float*)d_in[8];
  const float* W2  = (const float*)d_in[9];
  const float* b2  = (const float*)d_in[10];
  float* out = (float*)d_out;

  // workspace layout (~175 MB; proven available)
  float* ws_f  = (float*)d_ws;
  float* x2    = ws_f;                                 // N*64
  float* sarr  = x2 + (size_t)NROWS * 64;              // N (prescaled by log2e)
  float* sqarr = sarr + NROWS;                         // N
  float* l1c   = sqarr + NROWS;                        // N
  float* l2c   = l1c + NROWS;                          // N
  float* rs    = l2c + NROWS;                          // N
  float* ssum  = rs + NROWS;                           // N
  float* wsq   = ssum + NROWS;                         // N
  float* rspc  = wsq + NROWS;                          // 262144
  float* sspc  = rspc + 262144;                        // 262144
  float* wspc  = sspc + 262144;                        // 262144
  float* yp    = wspc + 262144;                        // 16*N*64
  short* x2bfT = (short*)(yp + (size_t)16 * NROWS * 64);   // N*64
  short* Bfrag = x2bfT + (size_t)NROWS * 64;           // 256*2048
  short* raw   = Bfrag + (size_t)256 * 2048;           // N*N bf16 (128 MB, row-major)

  hipLaunchKernelGGL(encoder_kernel, dim3(2048), dim3(256), 0, stream,
                     x, W10, b10, W11, b11, av, x2, sarr, sqarr, x2bfT);
  hipLaunchKernelGGL(prep16_kernel, dim3(256), dim3(256), 0, stream, x2bfT, Bfrag);
  hipLaunchKernelGGL(convert_kernel, dim3(2048), dim3(256), 0, stream,
                     A, sarr, sqarr, raw, rspc, sspc, wspc);
  hipLaunchKernelGGL(rowreduce_kernel, dim3(32), dim3(256), 0, stream,
                     rspc, sspc, wspc, rs, ssum, wsq);
  hipLaunchKernelGGL(gemm_lds_kernel, dim3(2048), dim3(256), 0, stream,
                     raw, Bfrag, yp);
  hipLaunchKernelGGL(finish_kernel, dim3(2048), dim3(256), 0, stream,
                     x2, sqarr, yp, rs, ssum, wsq, Wg, bg, W2, b2, out, l1c, l2c);
  hipLaunchKernelGGL(loss_kernel, dim3(1), dim3(256), 0, stream, l1c, l2c, out);
}

// Round 15
// 169.891 us; speedup vs baseline: 2.2415x; 1.4173x over previous
//
#include <hip/hip_runtime.h>
#include <hip/hip_bf16.h>
#include <cstddef>
#include <cstdint>

#define NROWS 8192
#define LOG2E 1.4426950408889634f

typedef __attribute__((ext_vector_type(8))) short bf16x8;
typedef __attribute__((ext_vector_type(4))) float f32x4;

#define EXP2(x) __builtin_amdgcn_exp2f(x)

__device__ __forceinline__ short f2bf(float f) {
  unsigned u = __float_as_uint(f);
  u += 0x7fffu + ((u >> 16) & 1u);   // RNE
  return (short)(u >> 16);
}
__device__ __forceinline__ float leaky_f(float v) { return fmaxf(v, 0.1f * v); }

union BFPair { __hip_bfloat162 h; unsigned u; };
__device__ __forceinline__ unsigned pack2(float a, float b) {
  BFPair p;
  p.h = __float22bfloat162_rn(make_float2(a, b));  // v_cvt_pk_bf16_f32
  return p.u;
}
__device__ __forceinline__ f32x4 ntload4(const float* p) {
  return __builtin_nontemporal_load((const f32x4*)p);
}

// ---------------- Kernel 1: MLP encoder: x[8192,256] -> x2, s(prescaled), sq, x2bfT --
extern "C" __global__ void __launch_bounds__(256)
encoder_kernel(const float* __restrict__ x, const float* __restrict__ W10,
               const float* __restrict__ b10, const float* __restrict__ W11,
               const float* __restrict__ b11, const float* __restrict__ avec,
               float* __restrict__ x2, float* __restrict__ sarr,
               float* __restrict__ sqarr, short* __restrict__ x2bfT) {
  __shared__ float xr[4][256];
  __shared__ float h1[4][128];
  const int t = threadIdx.x;
  const int r0 = blockIdx.x * 4;
#pragma unroll
  for (int r = 0; r < 4; ++r) xr[r][t] = x[(size_t)(r0 + r) * 256 + t];
  __syncthreads();
  if (t < 128) {
    float acc[4];
    const float b = b10[t];
#pragma unroll
    for (int r = 0; r < 4; ++r) acc[r] = b;
    const float* wrow = W10 + t * 256;
    for (int c = 0; c < 256; c += 4) {
      const float4 wv = *(const float4*)(wrow + c);
#pragma unroll
      for (int r = 0; r < 4; ++r) {
        acc[r] = fmaf(wv.x, xr[r][c], acc[r]);
        acc[r] = fmaf(wv.y, xr[r][c + 1], acc[r]);
        acc[r] = fmaf(wv.z, xr[r][c + 2], acc[r]);
        acc[r] = fmaf(wv.w, xr[r][c + 3], acc[r]);
      }
    }
#pragma unroll
    for (int r = 0; r < 4; ++r) h1[r][t] = leaky_f(acc[r]);
  }
  __syncthreads();
  if (t < 64) {
    float acc[4];
    const float b = b11[t];
#pragma unroll
    for (int r = 0; r < 4; ++r) acc[r] = b;
    const float* wrow = W11 + t * 128;
    for (int c = 0; c < 128; c += 4) {
      const float4 wv = *(const float4*)(wrow + c);
#pragma unroll
      for (int r = 0; r < 4; ++r) {
        acc[r] = fmaf(wv.x, h1[r][c], acc[r]);
        acc[r] = fmaf(wv.y, h1[r][c + 1], acc[r]);
        acc[r] = fmaf(wv.z, h1[r][c + 2], acc[r]);
        acc[r] = fmaf(wv.w, h1[r][c + 3], acc[r]);
      }
    }
    const float av = avec[t];
#pragma unroll
    for (int r = 0; r < 4; ++r) {
      const float v = leaky_f(acc[r]);
      x2[(size_t)(r0 + r) * 64 + t] = v;
      x2bfT[(size_t)t * NROWS + r0 + r] = f2bf(v);
      float ps = v * av, pq = v * v;
#pragma unroll
      for (int off = 1; off < 64; off <<= 1) {
        ps += __shfl_xor(ps, off);
        pq += __shfl_xor(pq, off);
      }
      if (t == 0) {
        sarr[r0 + r] = ps * LOG2E;          // exp(leaky(d)) = exp2(leaky(d*log2e))
        sqarr[r0 + r] = pq * (1.0f / 64.0f);
      }
    }
  }
}

// ---------------- Kernel 1b: B fragments (16x16x32 layout, contiguous) --------------
// Bfrag[S][nf][lane][8]: x2^T[n = nf*16 + (lane&15)][k = S*32 + (lane>>4)*8 + e]
extern "C" __global__ void __launch_bounds__(256)
prep16_kernel(const short* __restrict__ x2bfT, short* __restrict__ Bfrag) {
  const int S = blockIdx.x;           // 256 k-groups of 32
  const int t = threadIdx.x;
  const int nf = t >> 6, l = t & 63;
  const bf16x8 v = *(const bf16x8*)(x2bfT + (size_t)(nf * 16 + (l & 15)) * NROWS
                                    + S * 32 + (l >> 4) * 8);
  *(bf16x8*)(Bfrag + ((size_t)S * 4 + nf) * 512 + l * 8) = v;
}

// ---------------- Kernel 2: fused A-pass with chip-wide SLIDING column-panel sweep --
// Grid = 1024 blocks (exactly 4/CU, co-resident). Block b: FIXED slab = b&511
// (16 rows -> y and scalars accumulate in registers), sweeps cb = (b>>9) + 2k,
// k=0..15. At step k the whole chip reads cols [512k,512k+512) of ALL rows: a 16MB
// sliding column panel, 1KB contiguous per instruction, nt loads, no manual waits.
// Per tile: E (load+exp2+pack -> swizzled LDS frags) | bar | M (ds_read_b128 frag +
// L2-hot Bfrag + 8 MFMA) | bar. K-parity gives 2 partials, folded in finish.
extern "C" __global__ void __launch_bounds__(256)
fused_sweep_kernel(const float* __restrict__ A, const float* __restrict__ sarr,
                   const float* __restrict__ sqarr, const short* __restrict__ Bfrag,
                   float* __restrict__ yp, float* __restrict__ rsp,
                   float* __restrict__ ssp, float* __restrict__ wsp) {
  __shared__ __attribute__((aligned(16))) short stage[8][512];   // [S][unit*8+e] 8KB
  const int t = threadIdx.x, l = t & 63;
  const int w = __builtin_amdgcn_readfirstlane(t >> 6);
  const int b = blockIdx.x;
  const int slab = b & 511;
  const int par = b >> 9;              // K-parity partial index
  const int row0 = slab * 16;

  // E-phase lane constants: lane l holds cols k_t = l*4..+4 of the 256-col tile
  const int S_w = l >> 3;              // target S-block
  const int m_w = (l >> 1) & 3;        // k-granule within S
  const int e_w = l & 1;               // 8B half of the 16B unit
  // M-phase lane constants
  const int fr = l & 15, kg = l >> 4;

  float si[4];
#pragma unroll
  for (int q = 0; q < 4; ++q) si[q] = sarr[row0 + w * 4 + q];

  float prs[4] = {0.f,0.f,0.f,0.f}, pss[4] = {0.f,0.f,0.f,0.f}, pws[4] = {0.f,0.f,0.f,0.f};
  f32x4 acc = {0.f, 0.f, 0.f, 0.f};

#pragma unroll 1
  for (int k = 0; k < 16; ++k) {
    const int cb = par + 2 * k;
    const int c0 = cb * 256;
    // ---- phase E ----
    const f32x4 sj = *(const f32x4*)(sarr + c0 + l * 4);
    const f32x4 sq = *(const f32x4*)(sqarr + c0 + l * 4);
    f32x4 a4[4];
#pragma unroll
    for (int q = 0; q < 4; ++q)
      a4[q] = ntload4(A + (size_t)(row0 + w * 4 + q) * NROWS + c0 + l * 4);
#pragma unroll
    for (int q = 0; q < 4; ++q) {
      const int r = w * 4 + q;
      const float sif = si[q];
      const float d0 = sif - sj[0], d1 = sif - sj[1];
      const float d2 = sif - sj[2], d3 = sif - sj[3];
      const float r0 = EXP2(fmaxf(d0, 0.1f * d0)) * a4[q][0];
      const float r1 = EXP2(fmaxf(d1, 0.1f * d1)) * a4[q][1];
      const float r2 = EXP2(fmaxf(d2, 0.1f * d2)) * a4[q][2];
      const float r3 = EXP2(fmaxf(d3, 0.1f * d3)) * a4[q][3];
      prs[q] += (r0 + r1) + (r2 + r3);
      pss[q] = fmaf(r0, r0, pss[q]); pss[q] = fmaf(r1, r1, pss[q]);
      pss[q] = fmaf(r2, r2, pss[q]); pss[q] = fmaf(r3, r3, pss[q]);
      pws[q] = fmaf(r0, sq[0], pws[q]); pws[q] = fmaf(r1, sq[1], pws[q]);
      pws[q] = fmaf(r2, sq[2], pws[q]); pws[q] = fmaf(r3, sq[3], pws[q]);
      uint2 pk;
      pk.x = pack2(r0, r1);
      pk.y = pack2(r2, r3);
      // unit u = r + m_w*16; swizzled phys = u ^ ((S_w ^ (m_w<<1)) & 7)
      const int u = r + m_w * 16;
      const int phys = u ^ ((S_w ^ (m_w << 1)) & 7);
      *(uint2*)(&stage[S_w][phys * 8 + e_w * 4]) = pk;
    }
    __syncthreads();
    // ---- phase M: 8 k-steps, wave w = N-frag w ----
    const short* bp = Bfrag + ((size_t)(cb * 8) * 4 + w) * 512 + l * 8;
#pragma unroll
    for (int s = 0; s < 8; ++s) {
      const int phys_r = l ^ ((s ^ ((l >> 4) << 1)) & 7);
      const bf16x8 ar = *(const bf16x8*)(&stage[s][phys_r * 8]);
      const bf16x8 bv = *(const bf16x8*)(bp + (size_t)s * 2048);
      acc = __builtin_amdgcn_mfma_f32_16x16x32_bf16(ar, bv, acc, 0, 0, 0);
    }
    __syncthreads();
  }

  // ---- epilogue: y (C/D: col = lane&15, row = (lane>>4)*4 + reg) ----
  float* ypb = yp + (size_t)par * NROWS * 64;
#pragma unroll
  for (int ri = 0; ri < 4; ++ri)
    ypb[(size_t)(row0 + kg * 4 + ri) * 64 + w * 16 + fr] = acc[ri];
  // ---- row scalars: full 64-lane reduce, exact fp32 ----
#pragma unroll
  for (int q = 0; q < 4; ++q) {
    float a = prs[q], bq = pss[q], c = pws[q];
#pragma unroll
    for (int off = 1; off < 64; off <<= 1) {
      a += __shfl_xor(a, off);
      bq += __shfl_xor(bq, off);
      c += __shfl_xor(c, off);
    }
    if (l == 0) {
      const int gi = row0 + w * 4 + q;
      rsp[par * NROWS + gi] = a;
      ssp[par * NROWS + gi] = bq;
      wsp[par * NROWS + gi] = c;
    }
  }
}

// ---------------- Kernel 3: combine 2 partials, GNN layer + head, per-row losses ----
extern "C" __global__ void __launch_bounds__(256)
finish_kernel(const float* __restrict__ x2, const float* __restrict__ sqarr,
              const float* __restrict__ yp, const float* __restrict__ rsp,
              const float* __restrict__ ssp, const float* __restrict__ wsp,
              const float* __restrict__ Wg, const float* __restrict__ bg,
              const float* __restrict__ W2, const float* __restrict__ b2,
              float* __restrict__ outp, float* __restrict__ l1c, float* __restrict__ l2c) {
  __shared__ float hbuf[4][64];
  __shared__ float gbuf[4][64];
  const int t = threadIdx.x;
  const int w = t >> 6, lane = t & 63;
  const int i = blockIdx.x * 4 + w;

  const float yv = yp[(size_t)i * 64 + lane] + yp[(size_t)NROWS * 64 + (size_t)i * 64 + lane];
  const float rowsum = rsp[i] + rsp[NROWS + i];
  const float sumsq = ssp[i] + ssp[NROWS + i];
  const float wsq = wsp[i] + wsp[NROWS + i];
  const float inv = 1.0f / rowsum;
  hbuf[w][lane] = yv * inv;
  const float xv = x2[(size_t)i * 64 + lane];
  float xy = xv * yv;
#pragma unroll
  for (int off = 1; off < 64; off <<= 1) xy += __shfl_xor(xy, off);
  if (lane == 0) {
    l1c[i] = sqarr[i] + (wsq - (2.0f / 64.0f) * xy) * inv;
    l2c[i] = sumsq * inv * inv;
  }
  __syncthreads();
  float accg = bg[lane];
  {
    const float* wrow = Wg + lane * 64;
#pragma unroll 4
    for (int d = 0; d < 64; ++d) accg = fmaf(wrow[d], hbuf[w][d], accg);
  }
  gbuf[w][lane] = leaky_f(accg);
  __syncthreads();
  if (lane < 32) {
    float acco = b2[lane];
    const float* wrow = W2 + lane * 64;
#pragma unroll 4
    for (int d = 0; d < 64; ++d) acco = fmaf(wrow[d], gbuf[w][d], acco);
    outp[(size_t)i * 32 + lane] = acco;
  }
}

// ---------------- Kernel 4: scalar loss reduction -----------------------------------
extern "C" __global__ void __launch_bounds__(256)
loss_kernel(const float* __restrict__ l1c, const float* __restrict__ l2c,
            float* __restrict__ outp) {
  __shared__ float s1[256], s2[256];
  const int t = threadIdx.x;
  float a1 = 0.f, a2 = 0.f;
  for (int i = t * 4; i < NROWS; i += 1024) {
    const float4 v1 = *(const float4*)(l1c + i);
    const float4 v2 = *(const float4*)(l2c + i);
    a1 += (v1.x + v1.y) + (v1.z + v1.w);
    a2 += (v2.x + v2.y) + (v2.z + v2.w);
  }
  s1[t] = a1; s2[t] = a2;
  __syncthreads();
  for (int off = 128; off > 0; off >>= 1) {
    if (t < off) { s1[t] += s1[t + off]; s2[t] += s2[t + off]; }
    __syncthreads();
  }
  if (t == 0) {
    const float scale = 1.0f / ((float)NROWS * (float)NROWS);
    outp[NROWS * 32] = s1[0] * scale;
    outp[NROWS * 32 + 1] = s2[0] * scale;
  }
}

// ---------------- launch ------------------------------------------------------------
extern "C" void kernel_launch(void* const* d_in, const int* in_sizes, int n_in,
                              void* d_out, int out_size, void* d_ws, size_t ws_size,
                              hipStream_t stream) {
  const float* x   = (const float*)d_in[0];
  const float* A   = (const float*)d_in[1];
  const float* W10 = (const float*)d_in[2];
  const float* b10 = (const float*)d_in[3];
  const float* W11 = (const float*)d_in[4];
  const float* b11 = (const float*)d_in[5];
  const float* av  = (const float*)d_in[6];
  const float* Wg  = (const float*)d_in[7];
  const float* bg  = (const float*)d_in[8];
  const float* W2  = (const float*)d_in[9];
  const float* b2  = (const float*)d_in[10];
  float* out = (float*)d_out;

  // workspace layout (~14 MB)
  float* ws_f  = (float*)d_ws;
  float* x2    = ws_f;                                 // N*64
  float* sarr  = x2 + (size_t)NROWS * 64;              // N (prescaled by log2e)
  float* sqarr = sarr + NROWS;                         // N
  float* l1c   = sqarr + NROWS;                        // N
  float* l2c   = l1c + NROWS;                          // N
  float* yp    = l2c + NROWS;                          // 2*N*64
  float* rsp   = yp + (size_t)2 * NROWS * 64;          // 2*N
  float* ssp   = rsp + 2 * NROWS;                      // 2*N
  float* wsp   = ssp + 2 * NROWS;                      // 2*N
  short* x2bfT = (short*)(wsp + 2 * NROWS);            // N*64 bf16
  short* Bfrag = x2bfT + (size_t)NROWS * 64;           // 256*2048 bf16 (1MB)

  hipLaunchKernelGGL(encoder_kernel, dim3(2048), dim3(256), 0, stream,
                     x, W10, b10, W11, b11, av, x2, sarr, sqarr, x2bfT);
  hipLaunchKernelGGL(prep16_kernel, dim3(256), dim3(256), 0, stream, x2bfT, Bfrag);
  hipLaunchKernelGGL(fused_sweep_kernel, dim3(1024), dim3(256), 0, stream,
                     A, sarr, sqarr, Bfrag, yp, rsp, ssp, wsp);
  hipLaunchKernelGGL(finish_kernel, dim3(2048), dim3(256), 0, stream,
                     x2, sqarr, yp, rsp, ssp, wsp, Wg, bg, W2, b2, out, l1c, l2c);
  hipLaunchKernelGGL(loss_kernel, dim3(1), dim3(256), 0, stream, l1c, l2c, out);
}